// Round 1
// baseline (1064.246 us; speedup 1.0000x reference)
//
#include <hip/hip_runtime.h>
#include <hip/hip_bf16.h>
#include <math.h>

// Fused softmax(mask ? -1e10 : (in + bias) * scale) over last axis K=2048.
// Shapes: in [B=2,H=16,Q=2048,K=2048] f32; mask [B,1,Q,K] i32; bias [1,H,Q,K] f32.
// One 64-lane wave per row; row (2048 f32 = 8KB) lives entirely in registers
// (32 floats/lane). Single HBM pass: vectorized float4/int4 loads, wave
// shuffle reductions for max and sum, float4 stores. Memory-bound.

#define SCALE_F 0.08838834764831845f
#define MASK_NEG -1e10f

__global__ __launch_bounds__(256) void softmax_mask_bias_kernel(
    const float* __restrict__ in,
    const int* __restrict__ mask,
    const float* __restrict__ bias,
    float* __restrict__ out)
{
    // 4 waves per 256-thread block, one row per wave.
    const int row  = blockIdx.x * 4 + (threadIdx.x >> 6);   // [0, 65536)
    const int lane = threadIdx.x & 63;

    // row = ((b*16 + h) * 2048 + q)
    const int q  = row & 2047;
    const int bh = row >> 11;
    const int h  = bh & 15;
    const int b  = bh >> 4;

    const size_t K = 2048;
    const float4* __restrict__ inV   =
        reinterpret_cast<const float4*>(in   + (size_t)row * K);
    const float4* __restrict__ biasV =
        reinterpret_cast<const float4*>(bias + ((size_t)(h * 2048 + q)) * K);
    const int4*   __restrict__ maskV =
        reinterpret_cast<const int4*>(mask   + ((size_t)(b * 2048 + q)) * K);

    float vals[32];
    float mx = -INFINITY;

    #pragma unroll
    for (int j = 0; j < 8; ++j) {
        const int k4 = lane + j * 64;           // float4 index within row
        const float4 x  = inV[k4];
        const float4 bb = biasV[k4];
        const int4   mm = maskV[k4];
        const float v0 = mm.x ? MASK_NEG : (x.x + bb.x) * SCALE_F;
        const float v1 = mm.y ? MASK_NEG : (x.y + bb.y) * SCALE_F;
        const float v2 = mm.z ? MASK_NEG : (x.z + bb.z) * SCALE_F;
        const float v3 = mm.w ? MASK_NEG : (x.w + bb.w) * SCALE_F;
        vals[j * 4 + 0] = v0;
        vals[j * 4 + 1] = v1;
        vals[j * 4 + 2] = v2;
        vals[j * 4 + 3] = v3;
        mx = fmaxf(mx, fmaxf(fmaxf(v0, v1), fmaxf(v2, v3)));
    }

    // Wave-wide max reduction (64 lanes).
    #pragma unroll
    for (int off = 32; off >= 1; off >>= 1)
        mx = fmaxf(mx, __shfl_xor(mx, off));

    float sum = 0.0f;
    #pragma unroll
    for (int j = 0; j < 32; ++j) {
        const float e = expf(vals[j] - mx);
        vals[j] = e;
        sum += e;
    }

    // Wave-wide sum reduction.
    #pragma unroll
    for (int off = 32; off >= 1; off >>= 1)
        sum += __shfl_xor(sum, off);

    const float inv = 1.0f / sum;

    float4* __restrict__ outV = reinterpret_cast<float4*>(out + (size_t)row * K);
    #pragma unroll
    for (int j = 0; j < 8; ++j) {
        const int k4 = lane + j * 64;
        float4 o;
        o.x = vals[j * 4 + 0] * inv;
        o.y = vals[j * 4 + 1] * inv;
        o.z = vals[j * 4 + 2] * inv;
        o.w = vals[j * 4 + 3] * inv;
        outV[k4] = o;
    }
}

extern "C" void kernel_launch(void* const* d_in, const int* in_sizes, int n_in,
                              void* d_out, int out_size, void* d_ws, size_t ws_size,
                              hipStream_t stream) {
    const float* in   = (const float*)d_in[0];  // [2,16,2048,2048] f32
    const int*   mask = (const int*)  d_in[1];  // [2,1,2048,2048]  i32
    const float* bias = (const float*)d_in[2];  // [1,16,2048,2048] f32
    float* out = (float*)d_out;

    const int rows = 2 * 16 * 2048;             // 65536
    const int blocks = rows / 4;                // 4 waves (rows) per block
    softmax_mask_bias_kernel<<<blocks, 256, 0, stream>>>(in, mask, bias, out);
}